// Round 9
// baseline (528.918 us; speedup 1.0000x reference)
//
#include <hip/hip_runtime.h>
#include <hip/hip_cooperative_groups.h>
#include <stdint.h>

namespace cg = cooperative_groups;

#define M_NODES 4001
#define NW 63            // ceil(4001/64) bitmask words per row
#define DIM 128
#define THRESH 0.04f
#define MAXJ 512         // cap on |M2(i)| (mean ~80)
#define CAP 96           // cap on degree (mean ~21)
#define SENTINEL 4095    // bit 4095 is never set in m2row (word 63 == 0)
#define ADJ_RG 16        // row-groups of 256 rows
#define ADJ_BLOCKS (ADJ_RG * NW)                  // 1008
#define FV0_BLOCKS ((M_NODES * DIM + 255) / 256)  // 2001
#define PREP_VB (ADJ_BLOCKS + FV0_BLOCKS)         // 3009

// 6-step inclusive shfl scan over 64 lanes.
__device__ __forceinline__ int wave64_incl_scan(int v, int lane) {
#pragma unroll
    for (int d = 1; d < 64; d <<= 1) {
        int n = __shfl_up(v, d, 64);
        if (lane >= d) v += n;
    }
    return v;
}

// One cooperative kernel, three phases separated by grid.sync().
// Each phase's body is identical to the R7 per-block kernels, iterated
// grid-stride so per-phase parallelism is preserved (R4 lesson).
__global__ __launch_bounds__(256, 8)
void ccn_fused(const float* __restrict__ node_loc, const float* __restrict__ td,
               const float* __restrict__ depot, const float* __restrict__ W0w,
               const float* __restrict__ W0b,
               uint64_t* __restrict__ A, float* __restrict__ fv0,
               int* __restrict__ nbr, int* __restrict__ deg,
               float* __restrict__ fv1, float* __restrict__ out) {
    __shared__ float2 cand[64];          // phase 1
    __shared__ int slist[CAP];           // phase 2
    __shared__ float4 part[8][32];       // phase 2
    __shared__ int snn;                  // phase 2
    __shared__ uint64_t m2part[4][64];   // phase 3
    __shared__ uint64_t m2row[64];
    __shared__ int list1[CAP];
    __shared__ int list2[MAXJ];
    __shared__ float2 wacc[3][64];
    __shared__ int snn2;

    int tid = threadIdx.x;
    int lane = tid & 63, wave = tid >> 6;
    cg::grid_group grid = cg::this_grid();

    // ---------------- PHASE 1: adjacency tiles + fv0 ----------------
    for (int vb = blockIdx.x; vb < PREP_VB; vb += gridDim.x) {
        if (vb < ADJ_BLOCKS) {
            int rg = vb & (ADJ_RG - 1);
            int w  = vb >> 4;            // 0..62
            if (tid < 64) {
                int j = w * 64 + tid;
                float2 c;
                if (j == 0) { c.x = depot[0]; c.y = depot[1]; }
                else if (j < M_NODES) { c.x = node_loc[(j - 1) * 2]; c.y = node_loc[(j - 1) * 2 + 1]; }
                else { c.x = 1e9f; c.y = 1e9f; }
                cand[tid] = c;
            }
            int i = rg * 256 + tid;
            float xi = 0.f, yi = 0.f;
            if (i == 0) { xi = depot[0]; yi = depot[1]; }
            else if (i < M_NODES) { xi = node_loc[(i - 1) * 2]; yi = node_loc[(i - 1) * 2 + 1]; }
            __syncthreads();
            uint64_t m = 0;
#pragma unroll
            for (int b = 0; b < 64; ++b) {
#pragma clang fp contract(off)
                float dx = xi - cand[b].x;
                float dy = yi - cand[b].y;
                float xx = dx * dx;
                float yy = dy * dy;
                float d2 = xx + yy;
                if (sqrtf(d2) <= THRESH) m |= (1ull << b);
            }
            if (i < M_NODES) A[(size_t)i * NW + w] = m;
            __syncthreads();             // cand reused next vb
        } else {
            int idx = (vb - ADJ_BLOCKS) * 256 + tid;
            if (idx < M_NODES * DIM) {
                int i = idx >> 7;
                int d = idx & (DIM - 1);
                float lx, ly, t;
                if (i == 0) { lx = depot[0]; ly = depot[1]; t = 0.f; }
                else { lx = node_loc[(i - 1) * 2]; ly = node_loc[(i - 1) * 2 + 1]; t = td[i - 1]; }
                float v = fmaf(lx, W0w[d * 3 + 0], fmaf(ly, W0w[d * 3 + 1], fmaf(t, W0w[d * 3 + 2], W0b[d])));
                fv0[idx] = v > 0.f ? v : 0.f;
            }
        }
    }
    __threadfence();
    grid.sync();

    // ---------------- PHASE 2: CSR build + fv1 ----------------
    for (int i = blockIdx.x; i < M_NODES; i += gridDim.x) {
        if (tid < 64) {
            uint64_t m = (tid < NW) ? A[(size_t)i * NW + tid] : 0ull;
            int c = __popcll(m);
            int incl = wave64_incl_scan(c, tid);
            int oo = incl - c;
            int base = tid * 64;
            while (m) {
                int b = __builtin_ctzll(m);
                if (oo < CAP) { slist[oo] = base + b; nbr[(size_t)i * CAP + oo] = base + b; }
                ++oo;
                m &= m - 1;
            }
            int tot = __shfl(incl, 63, 64);
            if (tot > CAP) tot = CAP;
            if (tid == 0) { deg[i] = tot; snn = tot; }
            int s = tot + tid;                   // sentinel-pad slots [tot,64)
            if (s < 64) nbr[(size_t)i * CAP + s] = SENTINEL;
        }
        __syncthreads();
        int n1 = snn;
        int lane32 = tid & 31, g = tid >> 5;
        const float4* fv0v = (const float4*)fv0;
        float4 acc = {0.f, 0.f, 0.f, 0.f};
        for (int l = g; l < n1; l += 8) {
            float4 v = fv0v[(size_t)slist[l] * 32 + lane32];
            acc.x += v.x; acc.y += v.y; acc.z += v.z; acc.w += v.w;
        }
        part[g][lane32] = acc;
        __syncthreads();
        if (tid < 32) {
            float4 s = part[0][tid];
#pragma unroll
            for (int gg = 1; gg < 8; ++gg) {
                float4 p = part[gg][tid];
                s.x += p.x; s.y += p.y; s.z += p.z; s.w += p.w;
            }
            ((float4*)fv1)[(size_t)i * 32 + tid] = s;
        }
        __syncthreads();
    }
    __threadfence();
    grid.sync();

    // ---------------- PHASE 3: fv2 ----------------
    for (int i = blockIdx.x; i < M_NODES; i += gridDim.x) {
        int n1 = deg[i];
        if (tid < CAP) list1[tid] = (tid < n1) ? nbr[(size_t)i * CAP + tid] : 0;
        __syncthreads();

        // M2 row i = OR over j in N(i) of A row j, unroll-2.
        uint64_t o = 0;
        {
            int l = wave;
            for (; l + 4 < n1; l += 8) {
                uint64_t a0 = (lane < NW) ? A[(size_t)list1[l] * NW + lane] : 0ull;
                uint64_t a1 = (lane < NW) ? A[(size_t)list1[l + 4] * NW + lane] : 0ull;
                o |= a0 | a1;
            }
            if (l < n1) o |= (lane < NW) ? A[(size_t)list1[l] * NW + lane] : 0ull;
        }
        m2part[wave][lane] = o;
        __syncthreads();

        if (tid < 64) {
            uint64_t m = m2part[0][tid] | m2part[1][tid] | m2part[2][tid] | m2part[3][tid];
            m2row[tid] = m;
            int c = __popcll(m);
            int incl = wave64_incl_scan(c, tid);
            int oo = incl - c;
            int base = tid * 64;
            while (m) {
                int b = __builtin_ctzll(m);
                if (oo < MAXJ) list2[oo] = base + b;
                ++oo;
                m &= m - 1;
            }
            if (tid == 63) snn2 = incl < MAXJ ? incl : MAXJ;
        }
        __syncthreads();
        int n2 = snn2;

        // fused counts + weighted sum: wave per j, unroll-4.
        const float2* fv1v = (const float2*)fv1;
        float2 acc = {0.f, 0.f};
        {
            int l = wave;
            for (; l + 12 < n2; l += 16) {
                int j0 = list2[l];
                int j1 = list2[l + 4];
                int j2 = list2[l + 8];
                int j3 = list2[l + 12];
                int u0 = nbr[(size_t)j0 * CAP + lane];
                int u1 = nbr[(size_t)j1 * CAP + lane];
                int u2 = nbr[(size_t)j2 * CAP + lane];
                int u3 = nbr[(size_t)j3 * CAP + lane];
                float2 r0 = fv1v[(size_t)j0 * 64 + lane];
                float2 r1 = fv1v[(size_t)j1 * 64 + lane];
                float2 r2 = fv1v[(size_t)j2 * 64 + lane];
                float2 r3 = fv1v[(size_t)j3 * 64 + lane];
                bool p0 = (m2row[u0 >> 6] >> (u0 & 63)) & 1ull;
                bool p1 = (m2row[u1 >> 6] >> (u1 & 63)) & 1ull;
                bool p2 = (m2row[u2 >> 6] >> (u2 & 63)) & 1ull;
                bool p3 = (m2row[u3 >> 6] >> (u3 & 63)) & 1ull;
                float c0 = (float)__popcll(__ballot(p0));
                float c1 = (float)__popcll(__ballot(p1));
                float c2 = (float)__popcll(__ballot(p2));
                float c3 = (float)__popcll(__ballot(p3));
                acc.x = fmaf(c0, r0.x, acc.x); acc.y = fmaf(c0, r0.y, acc.y);
                acc.x = fmaf(c1, r1.x, acc.x); acc.y = fmaf(c1, r1.y, acc.y);
                acc.x = fmaf(c2, r2.x, acc.x); acc.y = fmaf(c2, r2.y, acc.y);
                acc.x = fmaf(c3, r3.x, acc.x); acc.y = fmaf(c3, r3.y, acc.y);
            }
            for (; l < n2; l += 4) {
                int j0 = list2[l];
                int u0 = nbr[(size_t)j0 * CAP + lane];
                float2 r0 = fv1v[(size_t)j0 * 64 + lane];
                bool p0 = (m2row[u0 >> 6] >> (u0 & 63)) & 1ull;
                float c0 = (float)__popcll(__ballot(p0));
                acc.x = fmaf(c0, r0.x, acc.x); acc.y = fmaf(c0, r0.y, acc.y);
            }
        }
        if (wave > 0) wacc[wave - 1][lane] = acc;
        __syncthreads();
        if (wave == 0) {
            float2 s0 = wacc[0][lane], s1 = wacc[1][lane], s2 = wacc[2][lane];
            float2 s = { acc.x + s0.x + s1.x + s2.x, acc.y + s0.y + s1.y + s2.y };
            ((float2*)out)[(size_t)i * 64 + lane] = s;
        }
        __syncthreads();
    }
}

extern "C" void kernel_launch(void* const* d_in, const int* in_sizes, int n_in,
                              void* d_out, int out_size, void* d_ws, size_t ws_size,
                              hipStream_t stream) {
    const float* node_loc = (const float*)d_in[0];  // [4000,2]
    const float* td       = (const float*)d_in[1];  // [4000,1]
    const float* depot    = (const float*)d_in[2];  // [1,2]
    const float* W0w      = (const float*)d_in[3];  // [128,3]
    const float* W0b      = (const float*)d_in[4];  // [128]
    float* out = (float*)d_out;                     // [4001,128]

    char* base = (char*)d_ws;
    size_t off = 0;
    auto carve = [&](size_t bytes) {
        char* p = base + off;
        off = (off + bytes + 511) & ~(size_t)511;
        return p;
    };
    uint64_t* A   = (uint64_t*)carve((size_t)M_NODES * NW * sizeof(uint64_t));  // ~2.0 MB
    float*    fv0 = (float*)   carve((size_t)M_NODES * DIM * sizeof(float));    // ~2.0 MB
    float*    fv1 = (float*)   carve((size_t)M_NODES * DIM * sizeof(float));    // ~2.0 MB
    int*      nbr = (int*)     carve((size_t)M_NODES * CAP * sizeof(int));      // ~1.5 MB
    int*      deg = (int*)     carve((size_t)M_NODES * sizeof(int));            // 16 KB

    // Co-resident grid (required by grid.sync): query blocks/CU, use all CUs.
    int bpc = 0;
    hipOccupancyMaxActiveBlocksPerMultiprocessor(&bpc, ccn_fused, 256, 0);
    if (bpc < 1) bpc = 1;
    if (bpc > 8) bpc = 8;
    int grid = 256 * bpc;   // target 2048 (8 blocks/CU at <=64 VGPR, ~12KB LDS)

    void* args[] = {(void*)&node_loc, (void*)&td, (void*)&depot, (void*)&W0w,
                    (void*)&W0b, (void*)&A, (void*)&fv0, (void*)&nbr,
                    (void*)&deg, (void*)&fv1, (void*)&out};
    hipLaunchCooperativeKernel((const void*)ccn_fused, dim3(grid), dim3(256),
                               args, 0, stream);
}

// Round 10
// 98.871 us; speedup vs baseline: 5.3496x; 5.3496x over previous
//
#include <hip/hip_runtime.h>
#include <stdint.h>

#define M_NODES 4001
#define NW 63            // ceil(4001/64) bitmask words per row
#define DIM 128
#define THRESH 0.04f
#define MAXJ 512         // cap on |M2(i)| (mean ~80)
#define CAP 96           // cap on degree (mean ~21, Poisson tail negligible)
#define SENTINEL 4095    // bit 4095 is never set in m2row (word 63 == 0)
#define ADJ_RG 16        // row-groups of 256 rows
#define ADJ_BLOCKS (ADJ_RG * NW)   // 1008
#define FV0_BLOCKS ((M_NODES * DIM + 255) / 256)  // 2001

// ---------- fused fv0 + adjacency ----------
// blocks [0, ADJ_BLOCKS): adjacency bitmask tile (row-group rg, word w).
// blocks [ADJ_BLOCKS, ...): fv0 = relu([loc,td] @ W0^T + b), flat elementwise.
// Adjacency predicate bit-matches numpy: d2 = dx*dx + dy*dy (contraction off),
// correctly-rounded sqrtf, <= 0.04f.
__global__ void prep_kernel(const float* __restrict__ node_loc,
                            const float* __restrict__ td,
                            const float* __restrict__ depot,
                            const float* __restrict__ W0w,
                            const float* __restrict__ W0b,
                            uint64_t* __restrict__ A,
                            float* __restrict__ fv0) {
    int tid = threadIdx.x;
    if (blockIdx.x < ADJ_BLOCKS) {
        __shared__ float2 cand[64];
        int rg = blockIdx.x & (ADJ_RG - 1);
        int w  = blockIdx.x >> 4;          // 0..62
        if (tid < 64) {
            int j = w * 64 + tid;
            float2 c;
            if (j == 0) { c.x = depot[0]; c.y = depot[1]; }
            else if (j < M_NODES) { c.x = node_loc[(j - 1) * 2]; c.y = node_loc[(j - 1) * 2 + 1]; }
            else { c.x = 1e9f; c.y = 1e9f; }
            cand[tid] = c;
        }
        int i = rg * 256 + tid;
        float xi = 0.f, yi = 0.f;
        if (i == 0) { xi = depot[0]; yi = depot[1]; }
        else if (i < M_NODES) { xi = node_loc[(i - 1) * 2]; yi = node_loc[(i - 1) * 2 + 1]; }
        __syncthreads();
        uint64_t m = 0;
#pragma unroll
        for (int b = 0; b < 64; ++b) {
#pragma clang fp contract(off)
            float dx = xi - cand[b].x;
            float dy = yi - cand[b].y;
            float xx = dx * dx;
            float yy = dy * dy;
            float d2 = xx + yy;
            if (sqrtf(d2) <= THRESH) m |= (1ull << b);
        }
        if (i < M_NODES) A[(size_t)i * NW + w] = m;
    } else {
        int idx = (blockIdx.x - ADJ_BLOCKS) * 256 + tid;
        if (idx >= M_NODES * DIM) return;
        int i = idx >> 7;
        int d = idx & (DIM - 1);
        float lx, ly, t;
        if (i == 0) { lx = depot[0]; ly = depot[1]; t = 0.f; }
        else { lx = node_loc[(i - 1) * 2]; ly = node_loc[(i - 1) * 2 + 1]; t = td[i - 1]; }
        float v = fmaf(lx, W0w[d * 3 + 0], fmaf(ly, W0w[d * 3 + 1], fmaf(t, W0w[d * 3 + 2], W0b[d])));
        fv0[idx] = v > 0.f ? v : 0.f;
    }
}

// 6-step inclusive shfl scan over 64 lanes.
__device__ __forceinline__ int wave64_incl_scan(int v, int lane) {
#pragma unroll
    for (int d = 1; d < 64; d <<= 1) {
        int n = __shfl_up(v, d, 64);
        if (lane >= d) v += n;
    }
    return v;
}

// ---------- fused CSR build + fv_1 ----------
// wave 0: scan A row -> deterministic neighbor list (LDS + global nbr, sentinel-
// padded to 64 entries). All 256 threads: fv1[i] = sum_j fv0[j],
// 8 groups x 32 lanes x float4 over coalesced fv0 rows.
__global__ void fv1csr_kernel(const uint64_t* __restrict__ A,
                              const float* __restrict__ fv0,
                              int* __restrict__ nbr, int* __restrict__ deg,
                              float* __restrict__ fv1) {
    __shared__ int slist[CAP];
    __shared__ float4 part[8][32];
    __shared__ int snn;
    int i = blockIdx.x, tid = threadIdx.x;
    if (tid < 64) {
        uint64_t m = (tid < NW) ? A[(size_t)i * NW + tid] : 0ull;
        int c = __popcll(m);
        int incl = wave64_incl_scan(c, tid);
        int oo = incl - c;
        int base = tid * 64;
        while (m) {
            int b = __builtin_ctzll(m);
            if (oo < CAP) { slist[oo] = base + b; nbr[(size_t)i * CAP + oo] = base + b; }
            ++oo;
            m &= m - 1;
        }
        int tot = __shfl(incl, 63, 64);
        if (tot > CAP) tot = CAP;
        if (tid == 0) { deg[i] = tot; snn = tot; }
        int s = tot + tid;                       // sentinel-pad slots [tot,64)
        if (s < 64) nbr[(size_t)i * CAP + s] = SENTINEL;
    }
    __syncthreads();
    int n1 = snn;
    int lane32 = tid & 31, g = tid >> 5;
    const float4* fv0v = (const float4*)fv0;     // row = 32 float4
    float4 acc = {0.f, 0.f, 0.f, 0.f};
    for (int l = g; l < n1; l += 8) {
        float4 v = fv0v[(size_t)slist[l] * 32 + lane32];
        acc.x += v.x; acc.y += v.y; acc.z += v.z; acc.w += v.w;
    }
    part[g][lane32] = acc;
    __syncthreads();
    if (tid < 32) {
        float4 s = part[0][tid];
#pragma unroll
        for (int gg = 1; gg < 8; ++gg) {
            float4 p = part[gg][tid];
            s.x += p.x; s.y += p.y; s.z += p.z; s.w += p.w;
        }
        ((float4*)fv1)[(size_t)i * 32 + tid] = s;
    }
}

// ---------- fv_2 ----------
// fv2[i] = sum_{j in M2(i)} |M2(i) ∩ N(j)| * fv1[j].
// M2 row built in-block (unroll-2 OR of neighbor A-rows); counts and weighted
// sum fused, wave-per-j, UNROLL-4: 8 independent loads in flight per round.
__global__ void fv2_kernel(const uint64_t* __restrict__ A,
                           const int* __restrict__ nbr, const int* __restrict__ deg,
                           const float* __restrict__ fv1, float* __restrict__ out) {
    __shared__ uint64_t m2part[4][64];
    __shared__ uint64_t m2row[64];
    __shared__ int list1[CAP];
    __shared__ int list2[MAXJ];
    __shared__ float2 wacc[3][64];
    __shared__ int snn2;

    int i = blockIdx.x, tid = threadIdx.x;
    int lane = tid & 63, wave = tid >> 6;
    int n1 = deg[i];
    if (tid < CAP) list1[tid] = (tid < n1) ? nbr[(size_t)i * CAP + tid] : 0;
    __syncthreads();

    // M2 row i = OR over j in N(i) of A row j (coalesced 504B rows), unroll-2.
    uint64_t o = 0;
    {
        int l = wave;
        for (; l + 4 < n1; l += 8) {
            uint64_t a0 = (lane < NW) ? A[(size_t)list1[l] * NW + lane] : 0ull;
            uint64_t a1 = (lane < NW) ? A[(size_t)list1[l + 4] * NW + lane] : 0ull;
            o |= a0 | a1;
        }
        if (l < n1) o |= (lane < NW) ? A[(size_t)list1[l] * NW + lane] : 0ull;
    }
    m2part[wave][lane] = o;
    __syncthreads();

    // wave 0: OR-combine, shfl-scan, deterministic enumerate of M2(i)
    if (tid < 64) {
        uint64_t m = m2part[0][tid] | m2part[1][tid] | m2part[2][tid] | m2part[3][tid];
        m2row[tid] = m;
        int c = __popcll(m);
        int incl = wave64_incl_scan(c, tid);
        int oo = incl - c;
        int base = tid * 64;
        while (m) {
            int b = __builtin_ctzll(m);
            if (oo < MAXJ) list2[oo] = base + b;
            ++oo;
            m &= m - 1;
        }
        if (tid == 63) snn2 = incl < MAXJ ? incl : MAXJ;
    }
    __syncthreads();
    int n2 = snn2;

    // fused counts + weighted sum: wave per j, unroll-4 (8 loads in flight).
    const float2* fv1v = (const float2*)fv1;     // row = 64 float2
    float2 acc = {0.f, 0.f};
    {
        int l = wave;
        for (; l + 12 < n2; l += 16) {
            int j0 = list2[l];                   // LDS broadcast
            int j1 = list2[l + 4];
            int j2 = list2[l + 8];
            int j3 = list2[l + 12];
            int u0 = nbr[(size_t)j0 * CAP + lane];       // coalesced 256B each
            int u1 = nbr[(size_t)j1 * CAP + lane];
            int u2 = nbr[(size_t)j2 * CAP + lane];
            int u3 = nbr[(size_t)j3 * CAP + lane];
            float2 r0 = fv1v[(size_t)j0 * 64 + lane];    // coalesced 512B each
            float2 r1 = fv1v[(size_t)j1 * 64 + lane];
            float2 r2 = fv1v[(size_t)j2 * 64 + lane];
            float2 r3 = fv1v[(size_t)j3 * 64 + lane];
            bool p0 = (m2row[u0 >> 6] >> (u0 & 63)) & 1ull;
            bool p1 = (m2row[u1 >> 6] >> (u1 & 63)) & 1ull;
            bool p2 = (m2row[u2 >> 6] >> (u2 & 63)) & 1ull;
            bool p3 = (m2row[u3 >> 6] >> (u3 & 63)) & 1ull;
            float c0 = (float)__popcll(__ballot(p0));    // exact small ints
            float c1 = (float)__popcll(__ballot(p1));
            float c2 = (float)__popcll(__ballot(p2));
            float c3 = (float)__popcll(__ballot(p3));
            acc.x = fmaf(c0, r0.x, acc.x); acc.y = fmaf(c0, r0.y, acc.y);
            acc.x = fmaf(c1, r1.x, acc.x); acc.y = fmaf(c1, r1.y, acc.y);
            acc.x = fmaf(c2, r2.x, acc.x); acc.y = fmaf(c2, r2.y, acc.y);
            acc.x = fmaf(c3, r3.x, acc.x); acc.y = fmaf(c3, r3.y, acc.y);
        }
        for (; l < n2; l += 4) {
            int j0 = list2[l];
            int u0 = nbr[(size_t)j0 * CAP + lane];
            float2 r0 = fv1v[(size_t)j0 * 64 + lane];
            bool p0 = (m2row[u0 >> 6] >> (u0 & 63)) & 1ull;
            float c0 = (float)__popcll(__ballot(p0));
            acc.x = fmaf(c0, r0.x, acc.x); acc.y = fmaf(c0, r0.y, acc.y);
        }
    }
    if (wave > 0) wacc[wave - 1][lane] = acc;
    __syncthreads();
    if (wave == 0) {
        float2 s0 = wacc[0][lane], s1 = wacc[1][lane], s2 = wacc[2][lane];
        float2 s = { acc.x + s0.x + s1.x + s2.x, acc.y + s0.y + s1.y + s2.y };
        ((float2*)out)[(size_t)i * 64 + lane] = s;   // coalesced 512B
    }
}

extern "C" void kernel_launch(void* const* d_in, const int* in_sizes, int n_in,
                              void* d_out, int out_size, void* d_ws, size_t ws_size,
                              hipStream_t stream) {
    const float* node_loc = (const float*)d_in[0];  // [4000,2]
    const float* td       = (const float*)d_in[1];  // [4000,1]
    const float* depot    = (const float*)d_in[2];  // [1,2]
    const float* W0w      = (const float*)d_in[3];  // [128,3]
    const float* W0b      = (const float*)d_in[4];  // [128]
    float* out = (float*)d_out;                     // [4001,128]

    char* base = (char*)d_ws;
    size_t off = 0;
    auto carve = [&](size_t bytes) {
        char* p = base + off;
        off = (off + bytes + 511) & ~(size_t)511;
        return p;
    };
    uint64_t* A   = (uint64_t*)carve((size_t)M_NODES * NW * sizeof(uint64_t));  // ~2.0 MB
    float*    fv0 = (float*)   carve((size_t)M_NODES * DIM * sizeof(float));    // ~2.0 MB
    float*    fv1 = (float*)   carve((size_t)M_NODES * DIM * sizeof(float));    // ~2.0 MB
    int*      nbr = (int*)     carve((size_t)M_NODES * CAP * sizeof(int));      // ~1.5 MB
    int*      deg = (int*)     carve((size_t)M_NODES * sizeof(int));            // 16 KB

    prep_kernel<<<ADJ_BLOCKS + FV0_BLOCKS, 256, 0, stream>>>(node_loc, td, depot,
                                                             W0w, W0b, A, fv0);
    fv1csr_kernel<<<M_NODES, 256, 0, stream>>>(A, fv0, nbr, deg, fv1);
    fv2_kernel<<<M_NODES, 256, 0, stream>>>(A, nbr, deg, fv1, out);
}